// Round 6
// baseline (575.961 us; speedup 1.0000x reference)
//
#include <hip/hip_runtime.h>

#define NN 100000
#define NE 400000
#define NR 3
#define DD 128
#define NROWS (NR * NN)
#define NEDGES (NR * NE)
#define SCAN_BLOCKS ((NROWS + 1023) / 1024)

typedef float f32x4 __attribute__((ext_vector_type(4)));
typedef __bf16 bf16x8 __attribute__((ext_vector_type(8)));

__device__ __forceinline__ unsigned short f2bf(float f) {
    unsigned int u = __float_as_uint(f);
    u += 0x7fff + ((u >> 16) & 1);          // round-to-nearest-even
    return (unsigned short)(u >> 16);
}

// ---------- prep: x -> bf16 ----------
__global__ __launch_bounds__(256) void cvt_x(const float* __restrict__ x,
                                             unsigned short* __restrict__ xb) {
    int i = blockIdx.x * 256 + threadIdx.x;          // NN*DD/8 = 1.6M threads
    const float4* xf = reinterpret_cast<const float4*>(x + (size_t)i * 8);
    float4 a = xf[0], b = xf[1];
    uint4 o;
    o.x = (unsigned)f2bf(a.x) | ((unsigned)f2bf(a.y) << 16);
    o.y = (unsigned)f2bf(a.z) | ((unsigned)f2bf(a.w) << 16);
    o.z = (unsigned)f2bf(b.x) | ((unsigned)f2bf(b.y) << 16);
    o.w = (unsigned)f2bf(b.z) | ((unsigned)f2bf(b.w) << 16);
    reinterpret_cast<uint4*>(xb)[i] = o;
}

// ---------- prep: combined transposed weights Wt[l][n][k] bf16 + summed bias ----------
__global__ __launch_bounds__(256) void prep_wb(const float* __restrict__ Wn,
                                               const float* __restrict__ Wr,
                                               const float* __restrict__ b,
                                               unsigned short* __restrict__ Wt,
                                               float* __restrict__ bias) {
    int t = blockIdx.x * 256 + threadIdx.x;
    if (t < 2 * 128 * 512) {
        int l = t >> 16;
        int rem = t & 65535;
        int n = rem >> 9;
        int k = rem & 511;
        int rk = k >> 7, kk = k & 127;
        float v;
        if (rk < 3) {
            v = Wn[(((size_t)l * 3 + rk) * 128 + kk) * 128 + n];
        } else {
            const float* WrL = Wr + (size_t)l * 3 * 128 * 128;
            v = WrL[kk * 128 + n] + WrL[128 * 128 + kk * 128 + n] + WrL[2 * 128 * 128 + kk * 128 + n];
        }
        Wt[((size_t)l * 128 + n) * 512 + k] = f2bf(v);
    } else if (t < 2 * 128 * 512 + 256) {
        int tt = t - 2 * 128 * 512;               // 0..255 = 2 layers x 128
        int l = tt >> 7, n = tt & 127;
        bias[tt] = b[l * 384 + n] + b[l * 384 + 128 + n] + b[l * 384 + 256 + n];
    }
}

// ---------- CSR build ----------
__global__ __launch_bounds__(256) void csr_count(const int* __restrict__ ei,
                                                 int* __restrict__ cnt) {
    int t = blockIdx.x * 256 + threadIdx.x;
    if (t >= NEDGES) return;
    int r = t / NE;
    int e = t - r * NE;
    int dst = ei[(r * 2 + 1) * NE + e];
    atomicAdd(&cnt[r * NN + dst], 1);
}

__global__ __launch_bounds__(256) void scan1(const int* __restrict__ cnt,
                                             int* __restrict__ row_start,
                                             int* __restrict__ bsum) {
    __shared__ int sh[256];
    int b0 = blockIdx.x * 1024;
    int t = threadIdx.x;
    int v[4];
    int s = 0;
    #pragma unroll
    for (int j = 0; j < 4; ++j) {
        int idx = b0 + t * 4 + j;
        v[j] = (idx < NROWS) ? cnt[idx] : 0;
        s += v[j];
    }
    sh[t] = s;
    __syncthreads();
    for (int off = 1; off < 256; off <<= 1) {
        int val = (t >= off) ? sh[t - off] : 0;
        __syncthreads();
        sh[t] += val;
        __syncthreads();
    }
    int excl = (t == 0) ? 0 : sh[t - 1];
    if (t == 255) bsum[blockIdx.x] = sh[255];
    #pragma unroll
    for (int j = 0; j < 4; ++j) {
        int idx = b0 + t * 4 + j;
        if (idx < NROWS) { row_start[idx] = excl; excl += v[j]; }
    }
}

__global__ __launch_bounds__(512) void scan2(int* __restrict__ bsum, int nb) {
    __shared__ int sh[512];
    int t = threadIdx.x;
    sh[t] = (t < nb) ? bsum[t] : 0;
    __syncthreads();
    for (int off = 1; off < 512; off <<= 1) {
        int val = (t >= off) ? sh[t - off] : 0;
        __syncthreads();
        sh[t] += val;
        __syncthreads();
    }
    int excl = (t == 0) ? 0 : sh[t - 1];
    if (t < nb) bsum[t] = excl;
}

// csr_fill folds in the block-sum add (scan3 removed); bucket stores BYTE offsets (src*256)
__global__ __launch_bounds__(256) void csr_fill(const int* __restrict__ ei,
                                                const int* __restrict__ row_start,
                                                const int* __restrict__ bsum,
                                                int* __restrict__ cursor,
                                                int* __restrict__ bucket) {
    int t = blockIdx.x * 256 + threadIdx.x;
    if (t >= NEDGES) return;
    int r = t / NE;
    int e = t - r * NE;
    int src = ei[(r * 2 + 0) * NE + e];
    int dst = ei[(r * 2 + 1) * NE + e];
    int i = r * NN + dst;
    int pos = row_start[i] + bsum[i >> 10] + atomicAdd(&cursor[i], 1);
    bucket[pos] = src << 8;                   // byte offset into bf16 row table
}

// ---------- aggregation: one 64-lane wave per CSR row, byte-offset indices ----------
__global__ __launch_bounds__(256) void gnn_gather(const unsigned short* __restrict__ h,
                                                  const int* __restrict__ bucket,
                                                  const int* __restrict__ row_start,
                                                  const int* __restrict__ bsum,
                                                  const int* __restrict__ cnt,
                                                  unsigned short* __restrict__ agg) {
    int wid = (blockIdx.x * 256 + threadIdx.x) >> 6;
    int lane = threadIdx.x & 63;
    if (wid >= NROWS) return;
    int base = row_start[wid] + bsum[wid >> 10];
    int deg = cnt[wid];
    const char* hb = (const char*)h;
    const unsigned int lo = lane * 4;
    float a0 = 0.f, a1 = 0.f, b0 = 0.f, b1 = 0.f;
    float c0 = 0.f, c1 = 0.f, d0 = 0.f, d1 = 0.f;
    int e = 0;
    for (; e + 8 <= deg; e += 8) {
        unsigned int o0 = (unsigned)bucket[base + e + 0] + lo;
        unsigned int o1 = (unsigned)bucket[base + e + 1] + lo;
        unsigned int o2 = (unsigned)bucket[base + e + 2] + lo;
        unsigned int o3 = (unsigned)bucket[base + e + 3] + lo;
        unsigned int o4 = (unsigned)bucket[base + e + 4] + lo;
        unsigned int o5 = (unsigned)bucket[base + e + 5] + lo;
        unsigned int o6 = (unsigned)bucket[base + e + 6] + lo;
        unsigned int o7 = (unsigned)bucket[base + e + 7] + lo;
        unsigned int v0 = *(const unsigned int*)(hb + o0);
        unsigned int v1 = *(const unsigned int*)(hb + o1);
        unsigned int v2 = *(const unsigned int*)(hb + o2);
        unsigned int v3 = *(const unsigned int*)(hb + o3);
        unsigned int v4 = *(const unsigned int*)(hb + o4);
        unsigned int v5 = *(const unsigned int*)(hb + o5);
        unsigned int v6 = *(const unsigned int*)(hb + o6);
        unsigned int v7 = *(const unsigned int*)(hb + o7);
        a0 += __uint_as_float(v0 << 16); a1 += __uint_as_float(v0 & 0xffff0000u);
        b0 += __uint_as_float(v1 << 16); b1 += __uint_as_float(v1 & 0xffff0000u);
        c0 += __uint_as_float(v2 << 16); c1 += __uint_as_float(v2 & 0xffff0000u);
        d0 += __uint_as_float(v3 << 16); d1 += __uint_as_float(v3 & 0xffff0000u);
        a0 += __uint_as_float(v4 << 16); a1 += __uint_as_float(v4 & 0xffff0000u);
        b0 += __uint_as_float(v5 << 16); b1 += __uint_as_float(v5 & 0xffff0000u);
        c0 += __uint_as_float(v6 << 16); c1 += __uint_as_float(v6 & 0xffff0000u);
        d0 += __uint_as_float(v7 << 16); d1 += __uint_as_float(v7 & 0xffff0000u);
    }
    for (; e + 4 <= deg; e += 4) {
        unsigned int o0 = (unsigned)bucket[base + e + 0] + lo;
        unsigned int o1 = (unsigned)bucket[base + e + 1] + lo;
        unsigned int o2 = (unsigned)bucket[base + e + 2] + lo;
        unsigned int o3 = (unsigned)bucket[base + e + 3] + lo;
        unsigned int v0 = *(const unsigned int*)(hb + o0);
        unsigned int v1 = *(const unsigned int*)(hb + o1);
        unsigned int v2 = *(const unsigned int*)(hb + o2);
        unsigned int v3 = *(const unsigned int*)(hb + o3);
        a0 += __uint_as_float(v0 << 16); a1 += __uint_as_float(v0 & 0xffff0000u);
        b0 += __uint_as_float(v1 << 16); b1 += __uint_as_float(v1 & 0xffff0000u);
        c0 += __uint_as_float(v2 << 16); c1 += __uint_as_float(v2 & 0xffff0000u);
        d0 += __uint_as_float(v3 << 16); d1 += __uint_as_float(v3 & 0xffff0000u);
    }
    for (; e < deg; ++e) {
        unsigned int o0 = (unsigned)bucket[base + e] + lo;
        unsigned int v0 = *(const unsigned int*)(hb + o0);
        a0 += __uint_as_float(v0 << 16); a1 += __uint_as_float(v0 & 0xffff0000u);
    }
    a0 = (a0 + b0) + (c0 + d0);
    a1 = (a1 + b1) + (c1 + d1);
    float sc = (deg > 0) ? (1.0f / (float)deg) : 0.0f;
    a0 *= sc; a1 *= sc;
    unsigned int o = (unsigned)f2bf(a0) | ((unsigned)f2bf(a1) << 16);
    reinterpret_cast<unsigned int*>(agg + (size_t)wid * DD)[lane] = o;
}

// ---------- MFMA GEMM, LDS-free: fragments loaded straight from global ----------
// BM=128, BN=128, 4 waves (2x2), each wave 64x64 = 4x4 frags of 16x16x32.
// B (128KB weight panel) is L2-resident; A has no intra-block reuse -> no staging.
template <int RELU>
__global__ __launch_bounds__(256, 2) void gemm_mfma(
    const unsigned short* __restrict__ aggb,  // [3*NN][128] bf16 (pre-divided means)
    const unsigned short* __restrict__ hb,    // [NN][128] bf16
    const unsigned short* __restrict__ Wt,    // [128 n][512 k] bf16 (transposed combined)
    const float* __restrict__ bias,           // [128]
    unsigned short* __restrict__ outb)        // [NN][128] bf16
{
    const int t = threadIdx.x;
    const int w = t >> 6, lane = t & 63;
    const int m0 = blockIdx.x * 128;
    const int wr = w >> 1, wc = w & 1;
    const int fr = lane & 15;        // fragment row/col
    const int fq = lane >> 4;        // k-granule (x8)
    f32x4 acc[4][4] = {};

    int arow[4];
    #pragma unroll
    for (int m = 0; m < 4; ++m) {
        int r = m0 + wr * 64 + m * 16 + fr;
        arow[m] = (r > NN - 1) ? (NN - 1) : r;   // clamp; stores guarded
    }

    #pragma unroll
    for (int s = 0; s < 16; ++s) {
        const int srcid = s >> 2;
        const int kl = (s & 3) * 32 + fq * 8;              // k within srcid's 128-block
        const unsigned short* Asrc = (srcid < 3) ? (aggb + (size_t)srcid * NN * DD) : hb;
        const int kg = srcid * 128 + kl;                   // global k in Wt
        bf16x8 af[4], bfr[4];
        #pragma unroll
        for (int m = 0; m < 4; ++m)
            af[m] = *reinterpret_cast<const bf16x8*>(Asrc + (size_t)arow[m] * DD + kl);
        #pragma unroll
        for (int n = 0; n < 4; ++n)
            bfr[n] = *reinterpret_cast<const bf16x8*>(Wt + (size_t)(wc * 64 + n * 16 + fr) * 512 + kg);
        #pragma unroll
        for (int m = 0; m < 4; ++m)
            #pragma unroll
            for (int n = 0; n < 4; ++n)
                acc[m][n] = __builtin_amdgcn_mfma_f32_16x16x32_bf16(af[m], bfr[n], acc[m][n], 0, 0, 0);
    }

    // epilogue: C/D layout col=lane&15, row=(lane>>4)*4+j
    #pragma unroll
    for (int n = 0; n < 4; ++n) {
        int col = wc * 64 + n * 16 + fr;
        float bs = bias[col];
        #pragma unroll
        for (int m = 0; m < 4; ++m) {
            int rbase = m0 + wr * 64 + m * 16 + fq * 4;
            #pragma unroll
            for (int j = 0; j < 4; ++j) {
                int row = rbase + j;
                if (row < NN) {
                    float v = acc[m][n][j] + bs;
                    if (RELU) v = fmaxf(v, 0.f);
                    outb[(size_t)row * DD + col] = f2bf(v);
                }
            }
        }
    }
}

// ---------- classifier: one wave per node row ----------
__global__ __launch_bounds__(256) void classify(const unsigned short* __restrict__ h2,
                                                const float* __restrict__ Wc,
                                                const float* __restrict__ bc,
                                                float* __restrict__ out) {
    int wid = (blockIdx.x * 256 + threadIdx.x) >> 6;
    int lane = threadIdx.x & 63;
    if (wid >= NN) return;
    float4 wc4 = reinterpret_cast<const float4*>(Wc)[lane];   // Wc[2l][0..1], Wc[2l+1][0..1]
    unsigned int v = reinterpret_cast<const unsigned int*>(h2 + (size_t)wid * DD)[lane];
    float v0 = __uint_as_float(v << 16);
    float v1 = __uint_as_float(v & 0xffff0000u);
    float p0 = v0 * wc4.x + v1 * wc4.z;
    float p1 = v0 * wc4.y + v1 * wc4.w;
    #pragma unroll
    for (int off = 1; off < 64; off <<= 1) {
        p0 += __shfl_xor(p0, off);
        p1 += __shfl_xor(p1, off);
    }
    if (lane == 0) {
        out[(size_t)wid * 2 + 0] = p0 + bc[0];
        out[(size_t)wid * 2 + 1] = p1 + bc[1];
    }
}

extern "C" void kernel_launch(void* const* d_in, const int* in_sizes, int n_in,
                              void* d_out, int out_size, void* d_ws, size_t ws_size,
                              hipStream_t stream) {
    const float* x  = (const float*)d_in[0];
    const int*   ei = (const int*)d_in[1];
    const float* Wn = (const float*)d_in[2];
    const float* Wr = (const float*)d_in[3];
    const float* b  = (const float*)d_in[4];
    const float* Wc = (const float*)d_in[5];
    const float* bc = (const float*)d_in[6];
    float* out = (float*)d_out;

    char* p = (char*)d_ws;
    unsigned short* aggb = (unsigned short*)p;  p += (size_t)NR * NN * DD * 2;
    unsigned short* xb   = (unsigned short*)p;  p += (size_t)NN * DD * 2;
    unsigned short* h1b  = (unsigned short*)p;  p += (size_t)NN * DD * 2;
    unsigned short* h2b  = (unsigned short*)p;  p += (size_t)NN * DD * 2;
    unsigned short* Wt   = (unsigned short*)p;  p += (size_t)2 * 128 * 512 * 2;
    float* bias          = (float*)p;           p += 2 * 128 * 4;
    int* bucket          = (int*)p;             p += (size_t)NEDGES * 4;
    int* cnt             = (int*)p;             p += (size_t)NROWS * 4;
    int* row_start       = (int*)p;             p += (size_t)NROWS * 4;
    int* cursor          = (int*)p;             p += (size_t)NROWS * 4;
    int* bsum            = (int*)p;             p += 512 * 4;

    hipMemsetAsync(cnt, 0, NROWS * sizeof(int), stream);
    hipMemsetAsync(cursor, 0, NROWS * sizeof(int), stream);

    // CSR build (shared by both layers)
    csr_count<<<(NEDGES + 255) / 256, 256, 0, stream>>>(ei, cnt);
    scan1<<<SCAN_BLOCKS, 256, 0, stream>>>(cnt, row_start, bsum);
    scan2<<<1, 512, 0, stream>>>(bsum, SCAN_BLOCKS);
    csr_fill<<<(NEDGES + 255) / 256, 256, 0, stream>>>(ei, row_start, bsum, cursor, bucket);

    // prep
    cvt_x<<<(NN * DD / 8 + 255) / 256, 256, 0, stream>>>(x, xb);
    prep_wb<<<(2 * 128 * 512 + 256 + 255) / 256, 256, 0, stream>>>(Wn, Wr, b, Wt, bias);

    const int gatherBlocks = (NROWS * 64) / 256;     // 75000
    const int gemmBlocks = (NN + 127) / 128;         // 782

    // Layer 0
    gnn_gather<<<gatherBlocks, 256, 0, stream>>>(xb, bucket, row_start, bsum, cnt, aggb);
    gemm_mfma<1><<<gemmBlocks, 256, 0, stream>>>(aggb, xb, Wt, bias, h1b);

    // Layer 1
    gnn_gather<<<gatherBlocks, 256, 0, stream>>>(h1b, bucket, row_start, bsum, cnt, aggb);
    gemm_mfma<0><<<gemmBlocks, 256, 0, stream>>>(aggb, h1b, Wt + (size_t)128 * 512,
                                                 bias + 128, h2b);

    // Classifier
    classify<<<(NN * 64 + 255) / 256, 256, 0, stream>>>(h2b, Wc, bc, out);
}

// Round 7
// 512.409 us; speedup vs baseline: 1.1240x; 1.1240x over previous
//
#include <hip/hip_runtime.h>

#define NN 100000
#define NE 400000
#define NR 3
#define DD 128
#define NROWS (NR * NN)
#define NEDGES (NR * NE)
#define SCAN_BLOCKS ((NROWS + 1023) / 1024)

typedef float f32x4 __attribute__((ext_vector_type(4)));
typedef __bf16 bf16x8 __attribute__((ext_vector_type(8)));

__device__ __forceinline__ unsigned short f2bf(float f) {
    unsigned int u = __float_as_uint(f);
    u += 0x7fff + ((u >> 16) & 1);          // round-to-nearest-even
    return (unsigned short)(u >> 16);
}

__device__ __forceinline__ void gload16(const void* g, void* l) {
    __builtin_amdgcn_global_load_lds(
        (const __attribute__((address_space(1))) void*)g,
        (__attribute__((address_space(3))) void*)l, 16, 0, 0);
}

// ---------- prep: x -> bf16 ----------
__global__ __launch_bounds__(256) void cvt_x(const float* __restrict__ x,
                                             unsigned short* __restrict__ xb) {
    int i = blockIdx.x * 256 + threadIdx.x;          // NN*DD/8 = 1.6M threads
    const float4* xf = reinterpret_cast<const float4*>(x + (size_t)i * 8);
    float4 a = xf[0], b = xf[1];
    uint4 o;
    o.x = (unsigned)f2bf(a.x) | ((unsigned)f2bf(a.y) << 16);
    o.y = (unsigned)f2bf(a.z) | ((unsigned)f2bf(a.w) << 16);
    o.z = (unsigned)f2bf(b.x) | ((unsigned)f2bf(b.y) << 16);
    o.w = (unsigned)f2bf(b.z) | ((unsigned)f2bf(b.w) << 16);
    reinterpret_cast<uint4*>(xb)[i] = o;
}

// ---------- prep: combined transposed weights Wt[l][n][k] bf16 + summed bias ----------
__global__ __launch_bounds__(256) void prep_wb(const float* __restrict__ Wn,
                                               const float* __restrict__ Wr,
                                               const float* __restrict__ b,
                                               unsigned short* __restrict__ Wt,
                                               float* __restrict__ bias) {
    int t = blockIdx.x * 256 + threadIdx.x;
    if (t < 2 * 128 * 512) {
        int l = t >> 16;
        int rem = t & 65535;
        int n = rem >> 9;
        int k = rem & 511;
        int rk = k >> 7, kk = k & 127;
        float v;
        if (rk < 3) {
            v = Wn[(((size_t)l * 3 + rk) * 128 + kk) * 128 + n];
        } else {
            const float* WrL = Wr + (size_t)l * 3 * 128 * 128;
            v = WrL[kk * 128 + n] + WrL[128 * 128 + kk * 128 + n] + WrL[2 * 128 * 128 + kk * 128 + n];
        }
        Wt[((size_t)l * 128 + n) * 512 + k] = f2bf(v);
    } else if (t < 2 * 128 * 512 + 256) {
        int tt = t - 2 * 128 * 512;               // 0..255 = 2 layers x 128
        int l = tt >> 7, n = tt & 127;
        bias[tt] = b[l * 384 + n] + b[l * 384 + 128 + n] + b[l * 384 + 256 + n];
    }
}

// ---------- CSR build ----------
__global__ __launch_bounds__(256) void csr_count(const int* __restrict__ ei,
                                                 int* __restrict__ cnt) {
    int t = blockIdx.x * 256 + threadIdx.x;
    if (t >= NEDGES) return;
    int r = t / NE;
    int e = t - r * NE;
    int dst = ei[(r * 2 + 1) * NE + e];
    atomicAdd(&cnt[r * NN + dst], 1);
}

__global__ __launch_bounds__(256) void scan1(const int* __restrict__ cnt,
                                             int* __restrict__ row_start,
                                             int* __restrict__ bsum) {
    __shared__ int sh[256];
    int b0 = blockIdx.x * 1024;
    int t = threadIdx.x;
    int v[4];
    int s = 0;
    #pragma unroll
    for (int j = 0; j < 4; ++j) {
        int idx = b0 + t * 4 + j;
        v[j] = (idx < NROWS) ? cnt[idx] : 0;
        s += v[j];
    }
    sh[t] = s;
    __syncthreads();
    for (int off = 1; off < 256; off <<= 1) {
        int val = (t >= off) ? sh[t - off] : 0;
        __syncthreads();
        sh[t] += val;
        __syncthreads();
    }
    int excl = (t == 0) ? 0 : sh[t - 1];
    if (t == 255) bsum[blockIdx.x] = sh[255];
    #pragma unroll
    for (int j = 0; j < 4; ++j) {
        int idx = b0 + t * 4 + j;
        if (idx < NROWS) { row_start[idx] = excl; excl += v[j]; }
    }
}

__global__ __launch_bounds__(512) void scan2(int* __restrict__ bsum, int nb) {
    __shared__ int sh[512];
    int t = threadIdx.x;
    sh[t] = (t < nb) ? bsum[t] : 0;
    __syncthreads();
    for (int off = 1; off < 512; off <<= 1) {
        int val = (t >= off) ? sh[t - off] : 0;
        __syncthreads();
        sh[t] += val;
        __syncthreads();
    }
    int excl = (t == 0) ? 0 : sh[t - 1];
    if (t < nb) bsum[t] = excl;
}

// csr_fill folds in the block-sum add; bucket stores BYTE offsets (src*256)
__global__ __launch_bounds__(256) void csr_fill(const int* __restrict__ ei,
                                                const int* __restrict__ row_start,
                                                const int* __restrict__ bsum,
                                                int* __restrict__ cursor,
                                                int* __restrict__ bucket) {
    int t = blockIdx.x * 256 + threadIdx.x;
    if (t >= NEDGES) return;
    int r = t / NE;
    int e = t - r * NE;
    int src = ei[(r * 2 + 0) * NE + e];
    int dst = ei[(r * 2 + 1) * NE + e];
    int i = r * NN + dst;
    int pos = row_start[i] + bsum[i >> 10] + atomicAdd(&cursor[i], 1);
    bucket[pos] = src << 8;                   // byte offset into bf16 row table
}

// ---------- aggregation: one 64-lane wave per CSR row, byte-offset indices ----------
__global__ __launch_bounds__(256) void gnn_gather(const unsigned short* __restrict__ h,
                                                  const int* __restrict__ bucket,
                                                  const int* __restrict__ row_start,
                                                  const int* __restrict__ bsum,
                                                  const int* __restrict__ cnt,
                                                  unsigned short* __restrict__ agg) {
    int wid = (blockIdx.x * 256 + threadIdx.x) >> 6;
    int lane = threadIdx.x & 63;
    if (wid >= NROWS) return;
    int base = row_start[wid] + bsum[wid >> 10];
    int deg = cnt[wid];
    const char* hb = (const char*)h;
    const unsigned int lo = lane * 4;
    float a0 = 0.f, a1 = 0.f, b0 = 0.f, b1 = 0.f;
    float c0 = 0.f, c1 = 0.f, d0 = 0.f, d1 = 0.f;
    int e = 0;
    for (; e + 8 <= deg; e += 8) {
        unsigned int o0 = (unsigned)bucket[base + e + 0] + lo;
        unsigned int o1 = (unsigned)bucket[base + e + 1] + lo;
        unsigned int o2 = (unsigned)bucket[base + e + 2] + lo;
        unsigned int o3 = (unsigned)bucket[base + e + 3] + lo;
        unsigned int o4 = (unsigned)bucket[base + e + 4] + lo;
        unsigned int o5 = (unsigned)bucket[base + e + 5] + lo;
        unsigned int o6 = (unsigned)bucket[base + e + 6] + lo;
        unsigned int o7 = (unsigned)bucket[base + e + 7] + lo;
        unsigned int v0 = *(const unsigned int*)(hb + o0);
        unsigned int v1 = *(const unsigned int*)(hb + o1);
        unsigned int v2 = *(const unsigned int*)(hb + o2);
        unsigned int v3 = *(const unsigned int*)(hb + o3);
        unsigned int v4 = *(const unsigned int*)(hb + o4);
        unsigned int v5 = *(const unsigned int*)(hb + o5);
        unsigned int v6 = *(const unsigned int*)(hb + o6);
        unsigned int v7 = *(const unsigned int*)(hb + o7);
        a0 += __uint_as_float(v0 << 16); a1 += __uint_as_float(v0 & 0xffff0000u);
        b0 += __uint_as_float(v1 << 16); b1 += __uint_as_float(v1 & 0xffff0000u);
        c0 += __uint_as_float(v2 << 16); c1 += __uint_as_float(v2 & 0xffff0000u);
        d0 += __uint_as_float(v3 << 16); d1 += __uint_as_float(v3 & 0xffff0000u);
        a0 += __uint_as_float(v4 << 16); a1 += __uint_as_float(v4 & 0xffff0000u);
        b0 += __uint_as_float(v5 << 16); b1 += __uint_as_float(v5 & 0xffff0000u);
        c0 += __uint_as_float(v6 << 16); c1 += __uint_as_float(v6 & 0xffff0000u);
        d0 += __uint_as_float(v7 << 16); d1 += __uint_as_float(v7 & 0xffff0000u);
    }
    for (; e + 4 <= deg; e += 4) {
        unsigned int o0 = (unsigned)bucket[base + e + 0] + lo;
        unsigned int o1 = (unsigned)bucket[base + e + 1] + lo;
        unsigned int o2 = (unsigned)bucket[base + e + 2] + lo;
        unsigned int o3 = (unsigned)bucket[base + e + 3] + lo;
        unsigned int v0 = *(const unsigned int*)(hb + o0);
        unsigned int v1 = *(const unsigned int*)(hb + o1);
        unsigned int v2 = *(const unsigned int*)(hb + o2);
        unsigned int v3 = *(const unsigned int*)(hb + o3);
        a0 += __uint_as_float(v0 << 16); a1 += __uint_as_float(v0 & 0xffff0000u);
        b0 += __uint_as_float(v1 << 16); b1 += __uint_as_float(v1 & 0xffff0000u);
        c0 += __uint_as_float(v2 << 16); c1 += __uint_as_float(v2 & 0xffff0000u);
        d0 += __uint_as_float(v3 << 16); d1 += __uint_as_float(v3 & 0xffff0000u);
    }
    for (; e < deg; ++e) {
        unsigned int o0 = (unsigned)bucket[base + e] + lo;
        unsigned int v0 = *(const unsigned int*)(hb + o0);
        a0 += __uint_as_float(v0 << 16); a1 += __uint_as_float(v0 & 0xffff0000u);
    }
    a0 = (a0 + b0) + (c0 + d0);
    a1 = (a1 + b1) + (c1 + d1);
    float sc = (deg > 0) ? (1.0f / (float)deg) : 0.0f;
    a0 *= sc; a1 *= sc;
    unsigned int o = (unsigned)f2bf(a0) | ((unsigned)f2bf(a1) << 16);
    reinterpret_cast<unsigned int*>(agg + (size_t)wid * DD)[lane] = o;
}

// ---------- MFMA GEMM: LDS double-buffered + XOR granule swizzle (bank-conflict-free) ----
// BM=128, BN=128, BK=32, 4 waves (2x2). LDS slot (row, g) holds global granule g^key(row),
// key(row) = (row ^ (row>>2)) & 3; linear gload_lds dest + pre-swizzled global source +
// swizzled ds_read (rule: both-sides-or-neither). Each 16-lane quarter hits every
// 16B bank-group exactly 2x -> conflict-free.
template <int RELU>
__global__ __launch_bounds__(256) void gemm_mfma(
    const unsigned short* __restrict__ aggb,  // [3*NN][128] bf16 (pre-divided means)
    const unsigned short* __restrict__ hb,    // [NN][128] bf16
    const unsigned short* __restrict__ Wt,    // [128 n][512 k] bf16 (transposed combined)
    const float* __restrict__ bias,           // [128]
    unsigned short* __restrict__ outb)        // [NN][128] bf16
{
    __shared__ __align__(16) unsigned short As[2 * 128 * 32];
    __shared__ __align__(16) unsigned short Bs[2 * 128 * 32];
    const int t = threadIdx.x;
    const int w = t >> 6, lane = t & 63;
    const int m0 = blockIdx.x * 128;
    const int wr = w >> 1, wc = w & 1;
    const int fr = lane & 15;        // fragment row/col
    const int fq = lane >> 4;        // k-granule (x8)
    // staging: lane -> (row = lane>>2, slot granule = lane&3); source granule = slot ^ key(row)
    const int gsw = (((lane & 3) ^ ((lane >> 2) & 3) ^ ((lane >> 4) & 3))) * 8;
    // read-side: granule slot = fq ^ key(read_row), key depends on fr only
    const int rsw = (fq ^ ((fr ^ (fr >> 2)) & 3)) * 8;
    f32x4 acc[4][4] = {};

    auto stage = [&](int s, int buf) {
        const int srcid = s >> 2;
        const int k0 = (s & 3) * 32;
        const unsigned short* Asrc = (srcid < 3) ? (aggb + (size_t)srcid * NN * DD) : hb;
        #pragma unroll
        for (int i = 0; i < 2; ++i) {
            int row = i * 64 + w * 16 + (lane >> 2);
            int grow = m0 + row;
            if (grow > NN - 1) grow = NN - 1;
            const unsigned short* gA = Asrc + (size_t)grow * DD + k0 + gsw;
            gload16(gA, (char*)As + buf * 8192 + i * 4096 + w * 1024);
            const unsigned short* gB = Wt + (size_t)row * 512 + srcid * 128 + k0 + gsw;
            gload16(gB, (char*)Bs + buf * 8192 + i * 4096 + w * 1024);
        }
    };

    stage(0, 0);
    #pragma unroll
    for (int s = 0; s < 16; ++s) {
        const int cur = s & 1;
        __syncthreads();                       // vmcnt drain -> buf[cur] ready
        if (s + 1 < 16) stage(s + 1, cur ^ 1); // prefetch overlaps MFMA below
        const unsigned short* As_c = As + cur * 4096;
        const unsigned short* Bs_c = Bs + cur * 4096;
        bf16x8 af[4], bfr[4];
        #pragma unroll
        for (int m = 0; m < 4; ++m)
            af[m] = *reinterpret_cast<const bf16x8*>(As_c + (wr * 64 + m * 16 + fr) * 32 + rsw);
        #pragma unroll
        for (int n = 0; n < 4; ++n)
            bfr[n] = *reinterpret_cast<const bf16x8*>(Bs_c + (wc * 64 + n * 16 + fr) * 32 + rsw);
        #pragma unroll
        for (int m = 0; m < 4; ++m)
            #pragma unroll
            for (int n = 0; n < 4; ++n)
                acc[m][n] = __builtin_amdgcn_mfma_f32_16x16x32_bf16(af[m], bfr[n], acc[m][n], 0, 0, 0);
    }

    // epilogue: C/D layout col=lane&15, row=(lane>>4)*4+j
    #pragma unroll
    for (int n = 0; n < 4; ++n) {
        int col = wc * 64 + n * 16 + fr;
        float bs = bias[col];
        #pragma unroll
        for (int m = 0; m < 4; ++m) {
            int rbase = m0 + wr * 64 + m * 16 + fq * 4;
            #pragma unroll
            for (int j = 0; j < 4; ++j) {
                int row = rbase + j;
                if (row < NN) {
                    float v = acc[m][n][j] + bs;
                    if (RELU) v = fmaxf(v, 0.f);
                    outb[(size_t)row * DD + col] = f2bf(v);
                }
            }
        }
    }
}

// ---------- classifier: one wave per node row ----------
__global__ __launch_bounds__(256) void classify(const unsigned short* __restrict__ h2,
                                                const float* __restrict__ Wc,
                                                const float* __restrict__ bc,
                                                float* __restrict__ out) {
    int wid = (blockIdx.x * 256 + threadIdx.x) >> 6;
    int lane = threadIdx.x & 63;
    if (wid >= NN) return;
    float4 wc4 = reinterpret_cast<const float4*>(Wc)[lane];   // Wc[2l][0..1], Wc[2l+1][0..1]
    unsigned int v = reinterpret_cast<const unsigned int*>(h2 + (size_t)wid * DD)[lane];
    float v0 = __uint_as_float(v << 16);
    float v1 = __uint_as_float(v & 0xffff0000u);
    float p0 = v0 * wc4.x + v1 * wc4.z;
    float p1 = v0 * wc4.y + v1 * wc4.w;
    #pragma unroll
    for (int off = 1; off < 64; off <<= 1) {
        p0 += __shfl_xor(p0, off);
        p1 += __shfl_xor(p1, off);
    }
    if (lane == 0) {
        out[(size_t)wid * 2 + 0] = p0 + bc[0];
        out[(size_t)wid * 2 + 1] = p1 + bc[1];
    }
}

extern "C" void kernel_launch(void* const* d_in, const int* in_sizes, int n_in,
                              void* d_out, int out_size, void* d_ws, size_t ws_size,
                              hipStream_t stream) {
    const float* x  = (const float*)d_in[0];
    const int*   ei = (const int*)d_in[1];
    const float* Wn = (const float*)d_in[2];
    const float* Wr = (const float*)d_in[3];
    const float* b  = (const float*)d_in[4];
    const float* Wc = (const float*)d_in[5];
    const float* bc = (const float*)d_in[6];
    float* out = (float*)d_out;

    char* p = (char*)d_ws;
    unsigned short* aggb = (unsigned short*)p;  p += (size_t)NR * NN * DD * 2;
    unsigned short* xb   = (unsigned short*)p;  p += (size_t)NN * DD * 2;
    unsigned short* h1b  = (unsigned short*)p;  p += (size_t)NN * DD * 2;
    unsigned short* h2b  = (unsigned short*)p;  p += (size_t)NN * DD * 2;
    unsigned short* Wt   = (unsigned short*)p;  p += (size_t)2 * 128 * 512 * 2;
    float* bias          = (float*)p;           p += 2 * 128 * 4;
    int* bucket          = (int*)p;             p += (size_t)NEDGES * 4;
    int* cnt             = (int*)p;             p += (size_t)NROWS * 4;
    int* row_start       = (int*)p;             p += (size_t)NROWS * 4;
    int* cursor          = (int*)p;             p += (size_t)NROWS * 4;
    int* bsum            = (int*)p;             p += 512 * 4;

    hipMemsetAsync(cnt, 0, NROWS * sizeof(int), stream);
    hipMemsetAsync(cursor, 0, NROWS * sizeof(int), stream);

    // CSR build (shared by both layers)
    csr_count<<<(NEDGES + 255) / 256, 256, 0, stream>>>(ei, cnt);
    scan1<<<SCAN_BLOCKS, 256, 0, stream>>>(cnt, row_start, bsum);
    scan2<<<1, 512, 0, stream>>>(bsum, SCAN_BLOCKS);
    csr_fill<<<(NEDGES + 255) / 256, 256, 0, stream>>>(ei, row_start, bsum, cursor, bucket);

    // prep
    cvt_x<<<(NN * DD / 8 + 255) / 256, 256, 0, stream>>>(x, xb);
    prep_wb<<<(2 * 128 * 512 + 256 + 255) / 256, 256, 0, stream>>>(Wn, Wr, b, Wt, bias);

    const int gatherBlocks = (NROWS * 64) / 256;     // 75000
    const int gemmBlocks = (NN + 127) / 128;         // 782

    // Layer 0
    gnn_gather<<<gatherBlocks, 256, 0, stream>>>(xb, bucket, row_start, bsum, cnt, aggb);
    gemm_mfma<1><<<gemmBlocks, 256, 0, stream>>>(aggb, xb, Wt, bias, h1b);

    // Layer 1
    gnn_gather<<<gatherBlocks, 256, 0, stream>>>(h1b, bucket, row_start, bsum, cnt, aggb);
    gemm_mfma<0><<<gemmBlocks, 256, 0, stream>>>(aggb, h1b, Wt + (size_t)128 * 512,
                                                 bias + 128, h2b);

    // Classifier
    classify<<<(NN * 64 + 255) / 256, 256, 0, stream>>>(h2b, Wc, bc, out);
}

// Round 8
// 485.399 us; speedup vs baseline: 1.1866x; 1.0556x over previous
//
#include <hip/hip_runtime.h>

#define NN 100000
#define NE 400000
#define NR 3
#define DD 128
#define NROWS (NR * NN)
#define NEDGES (NR * NE)
#define SCAN_BLOCKS ((NROWS + 1023) / 1024)

typedef float f32x4 __attribute__((ext_vector_type(4)));
typedef __bf16 bf16x8 __attribute__((ext_vector_type(8)));

__device__ __forceinline__ unsigned short f2bf(float f) {
    unsigned int u = __float_as_uint(f);
    u += 0x7fff + ((u >> 16) & 1);          // round-to-nearest-even
    return (unsigned short)(u >> 16);
}

__device__ __forceinline__ void gload16(const void* g, void* l) {
    __builtin_amdgcn_global_load_lds(
        (const __attribute__((address_space(1))) void*)g,
        (__attribute__((address_space(3))) void*)l, 16, 0, 0);
}

// ---------- fused prep: zero cnt+cursor | x->bf16 | Wt2 | bias ----------
// regions by blockIdx: [0,6250) cvt_x; [6250,6762) Wt2; 6762 bias; [6763,7349) zero
#define NB_CVT 6250
#define NB_WT 512
#define NB_ZERO 586
__global__ __launch_bounds__(256) void prep_all(const float* __restrict__ x,
                                                const float* __restrict__ Wn,
                                                const float* __restrict__ Wr,
                                                const float* __restrict__ b,
                                                unsigned short* __restrict__ xb,
                                                unsigned short* __restrict__ Wt2,
                                                float* __restrict__ bias,
                                                unsigned int* __restrict__ zbase) {
    int bid = blockIdx.x;
    int tid = threadIdx.x;
    if (bid < NB_CVT) {
        int i = bid * 256 + tid;                       // 1.6M exact
        const float4* xf = reinterpret_cast<const float4*>(x + (size_t)i * 8);
        float4 a = xf[0], bv = xf[1];
        uint4 o;
        o.x = (unsigned)f2bf(a.x) | ((unsigned)f2bf(a.y) << 16);
        o.y = (unsigned)f2bf(a.z) | ((unsigned)f2bf(a.w) << 16);
        o.z = (unsigned)f2bf(bv.x) | ((unsigned)f2bf(bv.y) << 16);
        o.w = (unsigned)f2bf(bv.z) | ((unsigned)f2bf(bv.w) << 16);
        reinterpret_cast<uint4*>(xb)[i] = o;
    } else if (bid < NB_CVT + NB_WT) {
        int t = (bid - NB_CVT) * 256 + tid;            // 131072 exact
        int l = t >> 16;
        int rem = t & 65535;
        int n512 = rem >> 7;                            // rk*128+n
        int kk = rem & 127;
        int rk = n512 >> 7, n = n512 & 127;
        float v;
        if (rk < 3) {
            v = Wn[(((size_t)l * 3 + rk) * 128 + kk) * 128 + n];
        } else {
            const float* WrL = Wr + (size_t)l * 3 * 128 * 128;
            v = WrL[kk * 128 + n] + WrL[128 * 128 + kk * 128 + n] + WrL[2 * 128 * 128 + kk * 128 + n];
        }
        Wt2[t] = f2bf(v);                               // [l][rk*128+n][kk]
    } else if (bid == NB_CVT + NB_WT) {
        int l = tid >> 7, n = tid & 127;                // 256 = 2 layers x 128
        bias[tid] = b[l * 384 + n] + b[l * 384 + 128 + n] + b[l * 384 + 256 + n];
    } else {
        int i = (bid - NB_CVT - NB_WT - 1) * 256 + tid; // zero cnt|cursor: 150000 uint4
        if (i < 150000) reinterpret_cast<uint4*>(zbase)[i] = make_uint4(0, 0, 0, 0);
    }
}

// ---------- CSR build ----------
__global__ __launch_bounds__(256) void csr_count(const int* __restrict__ ei,
                                                 int* __restrict__ cnt) {
    int t = blockIdx.x * 256 + threadIdx.x;
    if (t >= NEDGES) return;
    int r = t / NE;
    int e = t - r * NE;
    int dst = ei[(r * 2 + 1) * NE + e];
    atomicAdd(&cnt[r * NN + dst], 1);
}

__global__ __launch_bounds__(256) void scan1(const int* __restrict__ cnt,
                                             int* __restrict__ row_start,
                                             int* __restrict__ bsum) {
    __shared__ int sh[256];
    int b0 = blockIdx.x * 1024;
    int t = threadIdx.x;
    int v[4];
    int s = 0;
    #pragma unroll
    for (int j = 0; j < 4; ++j) {
        int idx = b0 + t * 4 + j;
        v[j] = (idx < NROWS) ? cnt[idx] : 0;
        s += v[j];
    }
    sh[t] = s;
    __syncthreads();
    for (int off = 1; off < 256; off <<= 1) {
        int val = (t >= off) ? sh[t - off] : 0;
        __syncthreads();
        sh[t] += val;
        __syncthreads();
    }
    int excl = (t == 0) ? 0 : sh[t - 1];
    if (t == 255) bsum[blockIdx.x] = sh[255];
    #pragma unroll
    for (int j = 0; j < 4; ++j) {
        int idx = b0 + t * 4 + j;
        if (idx < NROWS) { row_start[idx] = excl; excl += v[j]; }
    }
}

__global__ __launch_bounds__(512) void scan2(int* __restrict__ bsum, int nb) {
    __shared__ int sh[512];
    int t = threadIdx.x;
    sh[t] = (t < nb) ? bsum[t] : 0;
    __syncthreads();
    for (int off = 1; off < 512; off <<= 1) {
        int val = (t >= off) ? sh[t - off] : 0;
        __syncthreads();
        sh[t] += val;
        __syncthreads();
    }
    int excl = (t == 0) ? 0 : sh[t - 1];
    if (t < nb) bsum[t] = excl;
}

// bucket stores BYTE offsets into Y (1024B rows): src*1024
__global__ __launch_bounds__(256) void csr_fill(const int* __restrict__ ei,
                                                const int* __restrict__ row_start,
                                                const int* __restrict__ bsum,
                                                int* __restrict__ cursor,
                                                int* __restrict__ bucket) {
    int t = blockIdx.x * 256 + threadIdx.x;
    if (t >= NEDGES) return;
    int r = t / NE;
    int e = t - r * NE;
    int src = ei[(r * 2 + 0) * NE + e];
    int dst = ei[(r * 2 + 1) * NE + e];
    int i = r * NN + dst;
    int pos = row_start[i] + bsum[i >> 10] + atomicAdd(&cursor[i], 1);
    bucket[pos] = src << 10;
}

// ---------- MFMA GEMM: Y[NN][512] = A[NN][128] @ W_all ----------
// grid 3128: p = bid&3 (output panel), mb = bid>>2. BM=128, BN=128, BK=32,
// 4 waves (2x2), swizzled-LDS double buffer (proven round-7 structure).
__global__ __launch_bounds__(256) void gemm_y(
    const unsigned short* __restrict__ Ab,   // [NN][128] bf16
    const unsigned short* __restrict__ WtL,  // [4][128 n][128 k] bf16, layer base
    unsigned short* __restrict__ Yb)         // [NN][512] bf16
{
    __shared__ __align__(16) unsigned short As[2 * 128 * 32];
    __shared__ __align__(16) unsigned short Bs[2 * 128 * 32];
    const int t = threadIdx.x;
    const int w = t >> 6, lane = t & 63;
    const int bid = blockIdx.x;
    const int p = bid & 3;
    const int m0 = (bid >> 2) * 128;
    const unsigned short* WtP = WtL + p * 128 * 128;
    const int wr = w >> 1, wcol = w & 1;
    const int fr = lane & 15;
    const int fq = lane >> 4;
    const int gsw = (((lane & 3) ^ ((lane >> 2) & 3) ^ ((lane >> 4) & 3))) * 8;
    const int rsw = (fq ^ ((fr ^ (fr >> 2)) & 3)) * 8;
    f32x4 acc[4][4] = {};

    auto stage = [&](int s, int buf) {
        const int k0 = s * 32;
        #pragma unroll
        for (int i = 0; i < 2; ++i) {
            int row = i * 64 + w * 16 + (lane >> 2);
            int grow = m0 + row;
            if (grow > NN - 1) grow = NN - 1;
            const unsigned short* gA = Ab + (size_t)grow * DD + k0 + gsw;
            gload16(gA, (char*)As + buf * 8192 + i * 4096 + w * 1024);
            const unsigned short* gB = WtP + (size_t)row * 128 + k0 + gsw;
            gload16(gB, (char*)Bs + buf * 8192 + i * 4096 + w * 1024);
        }
    };

    stage(0, 0);
    #pragma unroll
    for (int s = 0; s < 4; ++s) {
        const int cur = s & 1;
        __syncthreads();
        if (s + 1 < 4) stage(s + 1, cur ^ 1);
        const unsigned short* As_c = As + cur * 4096;
        const unsigned short* Bs_c = Bs + cur * 4096;
        bf16x8 af[4], bfr[4];
        #pragma unroll
        for (int m = 0; m < 4; ++m)
            af[m] = *reinterpret_cast<const bf16x8*>(As_c + (wr * 64 + m * 16 + fr) * 32 + rsw);
        #pragma unroll
        for (int n = 0; n < 4; ++n)
            bfr[n] = *reinterpret_cast<const bf16x8*>(Bs_c + (wcol * 64 + n * 16 + fr) * 32 + rsw);
        #pragma unroll
        for (int m = 0; m < 4; ++m)
            #pragma unroll
            for (int n = 0; n < 4; ++n)
                acc[m][n] = __builtin_amdgcn_mfma_f32_16x16x32_bf16(af[m], bfr[n], acc[m][n], 0, 0, 0);
    }

    // epilogue: C/D layout col=lane&15, row=(lane>>4)*4+j; Y row stride 512
    #pragma unroll
    for (int n = 0; n < 4; ++n) {
        int col = p * 128 + wcol * 64 + n * 16 + fr;
        #pragma unroll
        for (int m = 0; m < 4; ++m) {
            int rbase = m0 + wr * 64 + m * 16 + fq * 4;
            #pragma unroll
            for (int j = 0; j < 4; ++j) {
                int row = rbase + j;
                if (row < NN) Yb[(size_t)row * 512 + col] = f2bf(acc[m][n][j]);
            }
        }
    }
}

// ---------- fused gather: one wave per dst node, all 3 relations + root + bias ----------
// h_out = [relu]( sum_r mean_r(Y panel r) + Y panel 3 (root) + bias )
// FINAL: classifier dot in-register -> logits (h2 never materialized)
template <int FINAL>
__global__ __launch_bounds__(256) void gather_fused(
    const unsigned short* __restrict__ Yb,
    const int* __restrict__ bucket,
    const int* __restrict__ row_start,
    const int* __restrict__ bsum,
    const int* __restrict__ cnt,
    const float* __restrict__ biasL,
    const float* __restrict__ Wc,
    const float* __restrict__ bc,
    unsigned short* __restrict__ hout,
    float* __restrict__ out)
{
    int wid = (blockIdx.x * 256 + threadIdx.x) >> 6;
    int lane = threadIdx.x & 63;
    if (wid >= NN) return;
    const char* Yc = (const char*)Yb;
    const unsigned int lo = lane * 4u;
    unsigned int rootv = *(const unsigned int*)(Yc + (size_t)wid * 1024u + 768u + lo);
    float t0 = __uint_as_float(rootv << 16);
    float t1 = __uint_as_float(rootv & 0xffff0000u);
    #pragma unroll
    for (int r = 0; r < 3; ++r) {
        int id = r * NN + wid;
        int base = row_start[id] + bsum[id >> 10];
        int deg = cnt[id];
        unsigned int rb = r * 256u + lo;
        float a0 = 0.f, a1 = 0.f, b0 = 0.f, b1 = 0.f;
        float c0 = 0.f, c1 = 0.f, d0 = 0.f, d1 = 0.f;
        int e = 0;
        for (; e + 4 <= deg; e += 4) {
            unsigned int o0 = (unsigned)bucket[base + e + 0] + rb;
            unsigned int o1 = (unsigned)bucket[base + e + 1] + rb;
            unsigned int o2 = (unsigned)bucket[base + e + 2] + rb;
            unsigned int o3 = (unsigned)bucket[base + e + 3] + rb;
            unsigned int v0 = *(const unsigned int*)(Yc + o0);
            unsigned int v1 = *(const unsigned int*)(Yc + o1);
            unsigned int v2 = *(const unsigned int*)(Yc + o2);
            unsigned int v3 = *(const unsigned int*)(Yc + o3);
            a0 += __uint_as_float(v0 << 16); a1 += __uint_as_float(v0 & 0xffff0000u);
            b0 += __uint_as_float(v1 << 16); b1 += __uint_as_float(v1 & 0xffff0000u);
            c0 += __uint_as_float(v2 << 16); c1 += __uint_as_float(v2 & 0xffff0000u);
            d0 += __uint_as_float(v3 << 16); d1 += __uint_as_float(v3 & 0xffff0000u);
        }
        for (; e < deg; ++e) {
            unsigned int o0 = (unsigned)bucket[base + e] + rb;
            unsigned int v0 = *(const unsigned int*)(Yc + o0);
            a0 += __uint_as_float(v0 << 16); a1 += __uint_as_float(v0 & 0xffff0000u);
        }
        float s0 = (a0 + b0) + (c0 + d0);
        float s1 = (a1 + b1) + (c1 + d1);
        float iv = (deg > 0) ? (1.0f / (float)deg) : 0.0f;
        t0 = fmaf(s0, iv, t0);
        t1 = fmaf(s1, iv, t1);
    }
    float2 bb = reinterpret_cast<const float2*>(biasL)[lane];
    t0 += bb.x;
    t1 += bb.y;
    if (!FINAL) {
        t0 = fmaxf(t0, 0.f);
        t1 = fmaxf(t1, 0.f);
        unsigned int o = (unsigned)f2bf(t0) | ((unsigned)f2bf(t1) << 16);
        reinterpret_cast<unsigned int*>(hout)[wid * 64 + lane] = o;
    } else {
        float4 w4 = reinterpret_cast<const float4*>(Wc)[lane];  // Wc[2l][0..1], Wc[2l+1][0..1]
        float p0 = t0 * w4.x + t1 * w4.z;
        float p1 = t0 * w4.y + t1 * w4.w;
        #pragma unroll
        for (int off = 1; off < 64; off <<= 1) {
            p0 += __shfl_xor(p0, off);
            p1 += __shfl_xor(p1, off);
        }
        if (lane == 0) {
            out[(size_t)wid * 2 + 0] = p0 + bc[0];
            out[(size_t)wid * 2 + 1] = p1 + bc[1];
        }
    }
}

extern "C" void kernel_launch(void* const* d_in, const int* in_sizes, int n_in,
                              void* d_out, int out_size, void* d_ws, size_t ws_size,
                              hipStream_t stream) {
    const float* x  = (const float*)d_in[0];
    const int*   ei = (const int*)d_in[1];
    const float* Wn = (const float*)d_in[2];
    const float* Wr = (const float*)d_in[3];
    const float* b  = (const float*)d_in[4];
    const float* Wc = (const float*)d_in[5];
    const float* bc = (const float*)d_in[6];
    float* out = (float*)d_out;

    char* p = (char*)d_ws;
    unsigned short* Yb  = (unsigned short*)p;  p += (size_t)NN * 512 * 2;        // 102.4 MB
    unsigned short* xb  = (unsigned short*)p;  p += (size_t)NN * DD * 2;         // 25.6 MB
    unsigned short* h1b = (unsigned short*)p;  p += (size_t)NN * DD * 2;         // 25.6 MB
    unsigned short* Wt2 = (unsigned short*)p;  p += (size_t)2 * 4 * 128 * 128 * 2;
    float* bias         = (float*)p;           p += 2 * 128 * 4;
    int* bucket         = (int*)p;             p += (size_t)NEDGES * 4;
    int* row_start      = (int*)p;             p += (size_t)NROWS * 4;
    int* bsum           = (int*)p;             p += 512 * 4;
    int* cnt            = (int*)p;             p += (size_t)NROWS * 4;           // cnt|cursor contiguous
    int* cursor         = (int*)p;             p += (size_t)NROWS * 4;

    // 1. fused prep (zero cnt+cursor, x->bf16, weights, bias)
    prep_all<<<NB_CVT + NB_WT + 1 + NB_ZERO, 256, 0, stream>>>(
        x, Wn, Wr, b, xb, Wt2, bias, (unsigned int*)cnt);

    // 2-5. CSR build (shared by both layers)
    csr_count<<<(NEDGES + 255) / 256, 256, 0, stream>>>(ei, cnt);
    scan1<<<SCAN_BLOCKS, 256, 0, stream>>>(cnt, row_start, bsum);
    scan2<<<1, 512, 0, stream>>>(bsum, SCAN_BLOCKS);
    csr_fill<<<(NEDGES + 255) / 256, 256, 0, stream>>>(ei, row_start, bsum, cursor, bucket);

    const int gemmBlocks = ((NN + 127) / 128) * 4;   // 3128
    const int gatherBlocks = NN * 64 / 256;          // 25000 exact

    // Layer 0: Y = xb @ [Wn|SumWr], then fused mean+root+bias+relu -> h1b
    gemm_y<<<gemmBlocks, 256, 0, stream>>>(xb, Wt2, Yb);
    gather_fused<0><<<gatherBlocks, 256, 0, stream>>>(Yb, bucket, row_start, bsum, cnt,
                                                      bias, nullptr, nullptr, h1b, nullptr);

    // Layer 1 + fused classifier
    gemm_y<<<gemmBlocks, 256, 0, stream>>>(h1b, Wt2 + (size_t)4 * 128 * 128, Yb);
    gather_fused<1><<<gatherBlocks, 256, 0, stream>>>(Yb, bucket, row_start, bsum, cnt,
                                                      bias + 128, Wc, bc, nullptr, out);
}

// Round 9
// 441.431 us; speedup vs baseline: 1.3048x; 1.0996x over previous
//
#include <hip/hip_runtime.h>

#define NN 100000
#define NE 400000
#define NR 3
#define DD 128
#define NROWS (NR * NN)
#define NEDGES (NR * NE)
#define SCAN_BLOCKS ((NROWS + 1023) / 1024)

typedef float f32x4 __attribute__((ext_vector_type(4)));
typedef __bf16 bf16x8 __attribute__((ext_vector_type(8)));

__device__ __forceinline__ unsigned short f2bf(float f) {
    unsigned int u = __float_as_uint(f);
    u += 0x7fff + ((u >> 16) & 1);          // round-to-nearest-even
    return (unsigned short)(u >> 16);
}
__device__ __forceinline__ float bflo(unsigned int u) { return __uint_as_float(u << 16); }
__device__ __forceinline__ float bfhi(unsigned int u) { return __uint_as_float(u & 0xffff0000u); }

__device__ __forceinline__ void gload16(const void* g, void* l) {
    __builtin_amdgcn_global_load_lds(
        (const __attribute__((address_space(1))) void*)g,
        (__attribute__((address_space(3))) void*)l, 16, 0, 0);
}

// ---------- fused prep: zero cnt+cursor | x->bf16 | Wt2 | bias ----------
#define NB_CVT 6250
#define NB_WT 512
#define NB_ZERO 586
__global__ __launch_bounds__(256) void prep_all(const float* __restrict__ x,
                                                const float* __restrict__ Wn,
                                                const float* __restrict__ Wr,
                                                const float* __restrict__ b,
                                                unsigned short* __restrict__ xb,
                                                unsigned short* __restrict__ Wt2,
                                                float* __restrict__ bias,
                                                unsigned int* __restrict__ zbase) {
    int bid = blockIdx.x;
    int tid = threadIdx.x;
    if (bid < NB_CVT) {
        int i = bid * 256 + tid;                       // 1.6M exact
        const float4* xf = reinterpret_cast<const float4*>(x + (size_t)i * 8);
        float4 a = xf[0], bv = xf[1];
        uint4 o;
        o.x = (unsigned)f2bf(a.x) | ((unsigned)f2bf(a.y) << 16);
        o.y = (unsigned)f2bf(a.z) | ((unsigned)f2bf(a.w) << 16);
        o.z = (unsigned)f2bf(bv.x) | ((unsigned)f2bf(bv.y) << 16);
        o.w = (unsigned)f2bf(bv.z) | ((unsigned)f2bf(bv.w) << 16);
        reinterpret_cast<uint4*>(xb)[i] = o;
    } else if (bid < NB_CVT + NB_WT) {
        int t = (bid - NB_CVT) * 256 + tid;            // 131072 exact
        int l = t >> 16;
        int rem = t & 65535;
        int n512 = rem >> 7;                            // rk*128+n
        int kk = rem & 127;
        int rk = n512 >> 7, n = n512 & 127;
        float v;
        if (rk < 3) {
            v = Wn[(((size_t)l * 3 + rk) * 128 + kk) * 128 + n];
        } else {
            const float* WrL = Wr + (size_t)l * 3 * 128 * 128;
            v = WrL[kk * 128 + n] + WrL[128 * 128 + kk * 128 + n] + WrL[2 * 128 * 128 + kk * 128 + n];
        }
        Wt2[t] = f2bf(v);                               // [l][rk*128+n][kk]
    } else if (bid == NB_CVT + NB_WT) {
        int l = tid >> 7, n = tid & 127;                // 256 = 2 layers x 128
        bias[tid] = b[l * 384 + n] + b[l * 384 + 128 + n] + b[l * 384 + 256 + n];
    } else {
        int i = (bid - NB_CVT - NB_WT - 1) * 256 + tid; // zero cnt|cursor: 150000 uint4
        if (i < 150000) reinterpret_cast<uint4*>(zbase)[i] = make_uint4(0, 0, 0, 0);
    }
}

// ---------- CSR build (rows keyed dst*3 + r so each dst's edges are contiguous) ----------
__global__ __launch_bounds__(256) void csr_count(const int* __restrict__ ei,
                                                 int* __restrict__ cnt) {
    int t = blockIdx.x * 256 + threadIdx.x;
    if (t >= NEDGES) return;
    int r = t / NE;
    int e = t - r * NE;
    int dst = ei[(r * 2 + 1) * NE + e];
    atomicAdd(&cnt[dst * 3 + r], 1);
}

__global__ __launch_bounds__(256) void scan1(const int* __restrict__ cnt,
                                             int* __restrict__ row_start,
                                             int* __restrict__ bsum) {
    __shared__ int sh[256];
    int b0 = blockIdx.x * 1024;
    int t = threadIdx.x;
    int v[4];
    int s = 0;
    #pragma unroll
    for (int j = 0; j < 4; ++j) {
        int idx = b0 + t * 4 + j;
        v[j] = (idx < NROWS) ? cnt[idx] : 0;
        s += v[j];
    }
    sh[t] = s;
    __syncthreads();
    for (int off = 1; off < 256; off <<= 1) {
        int val = (t >= off) ? sh[t - off] : 0;
        __syncthreads();
        sh[t] += val;
        __syncthreads();
    }
    int excl = (t == 0) ? 0 : sh[t - 1];
    if (t == 255) bsum[blockIdx.x] = sh[255];
    #pragma unroll
    for (int j = 0; j < 4; ++j) {
        int idx = b0 + t * 4 + j;
        if (idx < NROWS) { row_start[idx] = excl; excl += v[j]; }
    }
}

__global__ __launch_bounds__(512) void scan2(int* __restrict__ bsum, int nb) {
    __shared__ int sh[512];
    int t = threadIdx.x;
    sh[t] = (t < nb) ? bsum[t] : 0;
    __syncthreads();
    for (int off = 1; off < 512; off <<= 1) {
        int val = (t >= off) ? sh[t - off] : 0;
        __syncthreads();
        sh[t] += val;
        __syncthreads();
    }
    int excl = (t == 0) ? 0 : sh[t - 1];
    if (t < nb) bsum[t] = excl;
}

// bucket2[pos] = { byte offset of Y quarter-row (src*1024 + r*256), scale = 1/deg(r,dst) }
__global__ __launch_bounds__(256) void csr_fill(const int* __restrict__ ei,
                                                const int* __restrict__ row_start,
                                                const int* __restrict__ bsum,
                                                const int* __restrict__ cnt,
                                                int* __restrict__ cursor,
                                                int2* __restrict__ bucket2) {
    int t = blockIdx.x * 256 + threadIdx.x;
    if (t >= NEDGES) return;
    int r = t / NE;
    int e = t - r * NE;
    int src = ei[(r * 2 + 0) * NE + e];
    int dst = ei[(r * 2 + 1) * NE + e];
    int i = dst * 3 + r;
    int pos = row_start[i] + bsum[i >> 10] + atomicAdd(&cursor[i], 1);
    float sc = 1.0f / (float)cnt[i];          // deg >= 1 here (this edge exists)
    bucket2[pos] = make_int2((src << 10) | (r << 8), __float_as_int(sc));
}

// ---------- MFMA GEMM: Y[NN][512] = A[NN][128] @ W_all (round-7 proven structure) ----------
__global__ __launch_bounds__(256) void gemm_y(
    const unsigned short* __restrict__ Ab,   // [NN][128] bf16
    const unsigned short* __restrict__ WtL,  // [4][128 n][128 k] bf16, layer base
    unsigned short* __restrict__ Yb)         // [NN][512] bf16
{
    __shared__ __align__(16) unsigned short As[2 * 128 * 32];
    __shared__ __align__(16) unsigned short Bs[2 * 128 * 32];
    const int t = threadIdx.x;
    const int w = t >> 6, lane = t & 63;
    const int bid = blockIdx.x;
    const int p = bid & 3;
    const int m0 = (bid >> 2) * 128;
    const unsigned short* WtP = WtL + p * 128 * 128;
    const int wr = w >> 1, wcol = w & 1;
    const int fr = lane & 15;
    const int fq = lane >> 4;
    const int gsw = (((lane & 3) ^ ((lane >> 2) & 3) ^ ((lane >> 4) & 3))) * 8;
    const int rsw = (fq ^ ((fr ^ (fr >> 2)) & 3)) * 8;
    f32x4 acc[4][4] = {};

    auto stage = [&](int s, int buf) {
        const int k0 = s * 32;
        #pragma unroll
        for (int i = 0; i < 2; ++i) {
            int row = i * 64 + w * 16 + (lane >> 2);
            int grow = m0 + row;
            if (grow > NN - 1) grow = NN - 1;
            const unsigned short* gA = Ab + (size_t)grow * DD + k0 + gsw;
            gload16(gA, (char*)As + buf * 8192 + i * 4096 + w * 1024);
            const unsigned short* gB = WtP + (size_t)row * 128 + k0 + gsw;
            gload16(gB, (char*)Bs + buf * 8192 + i * 4096 + w * 1024);
        }
    };

    stage(0, 0);
    #pragma unroll
    for (int s = 0; s < 4; ++s) {
        const int cur = s & 1;
        __syncthreads();
        if (s + 1 < 4) stage(s + 1, cur ^ 1);
        const unsigned short* As_c = As + cur * 4096;
        const unsigned short* Bs_c = Bs + cur * 4096;
        bf16x8 af[4], bfr[4];
        #pragma unroll
        for (int m = 0; m < 4; ++m)
            af[m] = *reinterpret_cast<const bf16x8*>(As_c + (wr * 64 + m * 16 + fr) * 32 + rsw);
        #pragma unroll
        for (int n = 0; n < 4; ++n)
            bfr[n] = *reinterpret_cast<const bf16x8*>(Bs_c + (wcol * 64 + n * 16 + fr) * 32 + rsw);
        #pragma unroll
        for (int m = 0; m < 4; ++m)
            #pragma unroll
            for (int n = 0; n < 4; ++n)
                acc[m][n] = __builtin_amdgcn_mfma_f32_16x16x32_bf16(af[m], bfr[n], acc[m][n], 0, 0, 0);
    }

    #pragma unroll
    for (int n = 0; n < 4; ++n) {
        int col = p * 128 + wcol * 64 + n * 16 + fr;
        #pragma unroll
        for (int m = 0; m < 4; ++m) {
            int rbase = m0 + wr * 64 + m * 16 + fq * 4;
            #pragma unroll
            for (int j = 0; j < 4; ++j) {
                int row = rbase + j;
                if (row < NN) Yb[(size_t)row * 512 + col] = f2bf(acc[m][n][j]);
            }
        }
    }
}

// ---------- fused gather: one wave per dst, 16 lanes/row x 4 rows/instruction ----------
// acc = sum_e Y[src_e, panel r_e] * (1/deg) over ALL relations (flat loop, per-edge scale),
// + root panel + bias; relu / in-register classifier.
template <int FINAL>
__global__ __launch_bounds__(256) void gather_fused(
    const unsigned short* __restrict__ Yb,
    const int2* __restrict__ bucket2,
    const int* __restrict__ row_start,
    const int* __restrict__ bsum,
    const int* __restrict__ cnt,
    const float* __restrict__ biasL,
    const float* __restrict__ Wc,
    const float* __restrict__ bc,
    unsigned short* __restrict__ hout,
    float* __restrict__ out)
{
    int wid = (blockIdx.x * 256 + threadIdx.x) >> 6;
    int lane = threadIdx.x & 63;
    if (wid >= NN) return;
    const int g = lane >> 4;             // edge slot within 4-group
    const int q = lane & 15;             // 16B chunk within row
    const unsigned int qoff = q * 16u;
    const char* Yc = (const char*)Yb;
    const int r3 = wid * 3;
    const int base = row_start[r3] + bsum[r3 >> 10];
    const int degT = cnt[r3] + cnt[r3 + 1] + cnt[r3 + 2];

    float acc[8] = {};
    int e = 0;
    for (; e + 8 <= degT; e += 8) {
        int2 ma = bucket2[base + e + g];
        int2 mb = bucket2[base + e + 4 + g];
        uint4 va = *(const uint4*)(Yc + (unsigned)ma.x + qoff);
        uint4 vb = *(const uint4*)(Yc + (unsigned)mb.x + qoff);
        float sa = __int_as_float(ma.y);
        float sb = __int_as_float(mb.y);
        acc[0] = fmaf(bflo(va.x), sa, acc[0]); acc[1] = fmaf(bfhi(va.x), sa, acc[1]);
        acc[2] = fmaf(bflo(va.y), sa, acc[2]); acc[3] = fmaf(bfhi(va.y), sa, acc[3]);
        acc[4] = fmaf(bflo(va.z), sa, acc[4]); acc[5] = fmaf(bfhi(va.z), sa, acc[5]);
        acc[6] = fmaf(bflo(va.w), sa, acc[6]); acc[7] = fmaf(bfhi(va.w), sa, acc[7]);
        acc[0] = fmaf(bflo(vb.x), sb, acc[0]); acc[1] = fmaf(bfhi(vb.x), sb, acc[1]);
        acc[2] = fmaf(bflo(vb.y), sb, acc[2]); acc[3] = fmaf(bfhi(vb.y), sb, acc[3]);
        acc[4] = fmaf(bflo(vb.z), sb, acc[4]); acc[5] = fmaf(bfhi(vb.z), sb, acc[5]);
        acc[6] = fmaf(bflo(vb.w), sb, acc[6]); acc[7] = fmaf(bfhi(vb.w), sb, acc[7]);
    }
    for (; e < degT; e += 4) {
        if (e + g < degT) {
            int2 m = bucket2[base + e + g];
            uint4 v = *(const uint4*)(Yc + (unsigned)m.x + qoff);
            float s = __int_as_float(m.y);
            acc[0] = fmaf(bflo(v.x), s, acc[0]); acc[1] = fmaf(bfhi(v.x), s, acc[1]);
            acc[2] = fmaf(bflo(v.y), s, acc[2]); acc[3] = fmaf(bfhi(v.y), s, acc[3]);
            acc[4] = fmaf(bflo(v.z), s, acc[4]); acc[5] = fmaf(bfhi(v.z), s, acc[5]);
            acc[6] = fmaf(bflo(v.w), s, acc[6]); acc[7] = fmaf(bfhi(v.w), s, acc[7]);
        }
    }
    // cross-group reduce (groups hold disjoint edge subsets of the same columns)
    #pragma unroll
    for (int j = 0; j < 8; ++j) {
        acc[j] += __shfl_xor(acc[j], 16);
        acc[j] += __shfl_xor(acc[j], 32);
    }
    // root panel (p=3) + bias, added once post-reduce
    uint4 rv = *(const uint4*)(Yc + (size_t)wid * 1024u + 768u + qoff);
    acc[0] += bflo(rv.x); acc[1] += bfhi(rv.x);
    acc[2] += bflo(rv.y); acc[3] += bfhi(rv.y);
    acc[4] += bflo(rv.z); acc[5] += bfhi(rv.z);
    acc[6] += bflo(rv.w); acc[7] += bfhi(rv.w);
    float4 b0 = *(const float4*)(biasL + q * 8);
    float4 b1 = *(const float4*)(biasL + q * 8 + 4);
    acc[0] += b0.x; acc[1] += b0.y; acc[2] += b0.z; acc[3] += b0.w;
    acc[4] += b1.x; acc[5] += b1.y; acc[6] += b1.z; acc[7] += b1.w;

    if (!FINAL) {
        if (g == 0) {
            uint4 o;
            o.x = (unsigned)f2bf(fmaxf(acc[0], 0.f)) | ((unsigned)f2bf(fmaxf(acc[1], 0.f)) << 16);
            o.y = (unsigned)f2bf(fmaxf(acc[2], 0.f)) | ((unsigned)f2bf(fmaxf(acc[3], 0.f)) << 16);
            o.z = (unsigned)f2bf(fmaxf(acc[4], 0.f)) | ((unsigned)f2bf(fmaxf(acc[5], 0.f)) << 16);
            o.w = (unsigned)f2bf(fmaxf(acc[6], 0.f)) | ((unsigned)f2bf(fmaxf(acc[7], 0.f)) << 16);
            *reinterpret_cast<uint4*>(hout + (size_t)wid * DD + q * 8) = o;
        }
    } else {
        // classifier: cols q*8..q*8+7 per lane -> dot with Wc[col][0..1]
        float4 w0 = *(const float4*)(Wc + q * 16);
        float4 w1 = *(const float4*)(Wc + q * 16 + 4);
        float4 w2 = *(const float4*)(Wc + q * 16 + 8);
        float4 w3 = *(const float4*)(Wc + q * 16 + 12);
        float p0 = acc[0] * w0.x + acc[1] * w0.z + acc[2] * w1.x + acc[3] * w1.z +
                   acc[4] * w2.x + acc[5] * w2.z + acc[6] * w3.x + acc[7] * w3.z;
        float p1 = acc[0] * w0.y + acc[1] * w0.w + acc[2] * w1.y + acc[3] * w1.w +
                   acc[4] * w2.y + acc[5] * w2.w + acc[6] * w3.y + acc[7] * w3.w;
        #pragma unroll
        for (int off = 1; off < 16; off <<= 1) {
            p0 += __shfl_xor(p0, off);
            p1 += __shfl_xor(p1, off);
        }
        if (lane == 0) {
            out[(size_t)wid * 2 + 0] = p0 + bc[0];
            out[(size_t)wid * 2 + 1] = p1 + bc[1];
        }
    }
}

extern "C" void kernel_launch(void* const* d_in, const int* in_sizes, int n_in,
                              void* d_out, int out_size, void* d_ws, size_t ws_size,
                              hipStream_t stream) {
    const float* x  = (const float*)d_in[0];
    const int*   ei = (const int*)d_in[1];
    const float* Wn = (const float*)d_in[2];
    const float* Wr = (const float*)d_in[3];
    const float* b  = (const float*)d_in[4];
    const float* Wc = (const float*)d_in[5];
    const float* bc = (const float*)d_in[6];
    float* out = (float*)d_out;

    char* p = (char*)d_ws;
    unsigned short* Yb  = (unsigned short*)p;  p += (size_t)NN * 512 * 2;        // 102.4 MB
    unsigned short* xb  = (unsigned short*)p;  p += (size_t)NN * DD * 2;         // 25.6 MB
    unsigned short* h1b = (unsigned short*)p;  p += (size_t)NN * DD * 2;         // 25.6 MB
    unsigned short* Wt2 = (unsigned short*)p;  p += (size_t)2 * 4 * 128 * 128 * 2;
    float* bias         = (float*)p;           p += 2 * 128 * 4;
    int2* bucket2       = (int2*)p;            p += (size_t)NEDGES * 8;          // 9.6 MB
    int* row_start      = (int*)p;             p += (size_t)NROWS * 4;
    int* bsum           = (int*)p;             p += 512 * 4;
    int* cnt            = (int*)p;             p += (size_t)NROWS * 4;           // cnt|cursor contiguous
    int* cursor         = (int*)p;             p += (size_t)NROWS * 4;

    // 1. fused prep (zero cnt+cursor, x->bf16, weights, bias)
    prep_all<<<NB_CVT + NB_WT + 1 + NB_ZERO, 256, 0, stream>>>(
        x, Wn, Wr, b, xb, Wt2, bias, (unsigned int*)cnt);

    // 2-5. CSR build (shared by both layers)
    csr_count<<<(NEDGES + 255) / 256, 256, 0, stream>>>(ei, cnt);
    scan1<<<SCAN_BLOCKS, 256, 0, stream>>>(cnt, row_start, bsum);
    scan2<<<1, 512, 0, stream>>>(bsum, SCAN_BLOCKS);
    csr_fill<<<(NEDGES + 255) / 256, 256, 0, stream>>>(ei, row_start, bsum, cnt, cursor, bucket2);

    const int gemmBlocks = ((NN + 127) / 128) * 4;   // 3128
    const int gatherBlocks = NN * 64 / 256;          // 25000 exact

    // Layer 0
    gemm_y<<<gemmBlocks, 256, 0, stream>>>(xb, Wt2, Yb);
    gather_fused<0><<<gatherBlocks, 256, 0, stream>>>(Yb, bucket2, row_start, bsum, cnt,
                                                      bias, nullptr, nullptr, h1b, nullptr);

    // Layer 1 + fused classifier
    gemm_y<<<gemmBlocks, 256, 0, stream>>>(h1b, Wt2 + (size_t)4 * 128 * 128, Yb);
    gather_fused<1><<<gatherBlocks, 256, 0, stream>>>(Yb, bucket2, row_start, bsum, cnt,
                                                      bias + 128, Wc, bc, nullptr, out);
}

// Round 10
// 423.030 us; speedup vs baseline: 1.3615x; 1.0435x over previous
//
#include <hip/hip_runtime.h>

#define NN 100000
#define NE 400000
#define NR 3
#define DD 128
#define NROWS (NR * NN)
#define NEDGES (NR * NE)
#define SCAN_BLOCKS ((NROWS + 1023) / 1024)

typedef float f32x4 __attribute__((ext_vector_type(4)));
typedef __bf16 bf16x8 __attribute__((ext_vector_type(8)));

__device__ __forceinline__ unsigned short f2bf(float f) {
    unsigned int u = __float_as_uint(f);
    u += 0x7fff + ((u >> 16) & 1);          // round-to-nearest-even
    return (unsigned short)(u >> 16);
}
__device__ __forceinline__ float bflo(unsigned int u) { return __uint_as_float(u << 16); }
__device__ __forceinline__ float bfhi(unsigned int u) { return __uint_as_float(u & 0xffff0000u); }

__device__ __forceinline__ void gload16(const void* g, void* l) {
    __builtin_amdgcn_global_load_lds(
        (const __attribute__((address_space(1))) void*)g,
        (__attribute__((address_space(3))) void*)l, 16, 0, 0);
}

// ================= launch 1: [cvt_x | Wt2 | bias | csr_count] =================
#define NB_CVT 6250
#define NB_WT 512
#define NB_CNT 4688
__global__ __launch_bounds__(256) void prep_count(const float* __restrict__ x,
                                                  const float* __restrict__ Wn,
                                                  const float* __restrict__ Wr,
                                                  const float* __restrict__ b,
                                                  const int* __restrict__ ei,
                                                  unsigned short* __restrict__ xb,
                                                  unsigned short* __restrict__ Wt2,
                                                  float* __restrict__ bias,
                                                  int* __restrict__ cnt) {
    int bid = blockIdx.x;
    int tid = threadIdx.x;
    if (bid < NB_CVT) {
        int i = bid * 256 + tid;                       // 1.6M exact
        const float4* xf = reinterpret_cast<const float4*>(x + (size_t)i * 8);
        float4 a = xf[0], bv = xf[1];
        uint4 o;
        o.x = (unsigned)f2bf(a.x) | ((unsigned)f2bf(a.y) << 16);
        o.y = (unsigned)f2bf(a.z) | ((unsigned)f2bf(a.w) << 16);
        o.z = (unsigned)f2bf(bv.x) | ((unsigned)f2bf(bv.y) << 16);
        o.w = (unsigned)f2bf(bv.z) | ((unsigned)f2bf(bv.w) << 16);
        reinterpret_cast<uint4*>(xb)[i] = o;
    } else if (bid < NB_CVT + NB_WT) {
        int t = (bid - NB_CVT) * 256 + tid;            // 131072 exact
        int l = t >> 16;
        int rem = t & 65535;
        int n512 = rem >> 7;                            // rk*128+n
        int kk = rem & 127;
        int rk = n512 >> 7, n = n512 & 127;
        float v;
        if (rk < 3) {
            v = Wn[(((size_t)l * 3 + rk) * 128 + kk) * 128 + n];
        } else {
            const float* WrL = Wr + (size_t)l * 3 * 128 * 128;
            v = WrL[kk * 128 + n] + WrL[128 * 128 + kk * 128 + n] + WrL[2 * 128 * 128 + kk * 128 + n];
        }
        Wt2[t] = f2bf(v);                               // [l][rk*128+n][kk]
    } else if (bid == NB_CVT + NB_WT) {
        int l = tid >> 7, n = tid & 127;                // 256 = 2 layers x 128
        bias[tid] = b[l * 384 + n] + b[l * 384 + 128 + n] + b[l * 384 + 256 + n];
    } else {
        int t = (bid - NB_CVT - NB_WT - 1) * 256 + tid;
        if (t < NEDGES) {
            int r = t / NE;
            int e = t - r * NE;
            int dst = ei[(r * 2 + 1) * NE + e];
            atomicAdd(&cnt[dst * 3 + r], 1);            // rows keyed dst*3+r
        }
    }
}

// ================= scans =================
__global__ __launch_bounds__(256) void scan1(const int* __restrict__ cnt,
                                             int* __restrict__ row_start,
                                             int* __restrict__ bsum) {
    __shared__ int sh[256];
    int b0 = blockIdx.x * 1024;
    int t = threadIdx.x;
    int v[4];
    int s = 0;
    #pragma unroll
    for (int j = 0; j < 4; ++j) {
        int idx = b0 + t * 4 + j;
        v[j] = (idx < NROWS) ? cnt[idx] : 0;
        s += v[j];
    }
    sh[t] = s;
    __syncthreads();
    for (int off = 1; off < 256; off <<= 1) {
        int val = (t >= off) ? sh[t - off] : 0;
        __syncthreads();
        sh[t] += val;
        __syncthreads();
    }
    int excl = (t == 0) ? 0 : sh[t - 1];
    if (t == 255) bsum[blockIdx.x] = sh[255];
    #pragma unroll
    for (int j = 0; j < 4; ++j) {
        int idx = b0 + t * 4 + j;
        if (idx < NROWS) { row_start[idx] = excl; excl += v[j]; }
    }
}

__global__ __launch_bounds__(512) void scan2(int* __restrict__ bsum, int nb) {
    __shared__ int sh[512];
    int t = threadIdx.x;
    sh[t] = (t < nb) ? bsum[t] : 0;
    __syncthreads();
    for (int off = 1; off < 512; off <<= 1) {
        int val = (t >= off) ? sh[t - off] : 0;
        __syncthreads();
        sh[t] += val;
        __syncthreads();
    }
    int excl = (t == 0) ? 0 : sh[t - 1];
    if (t < nb) bsum[t] = excl;
}

// ================= launch 4: [csr_fill | gemm_y layer 0], block-interleaved ===========
#define NGEMM 3128          // (NN+127)/128 * 4 panels
#define NFILL 4688          // (NEDGES+255)/256

__device__ __forceinline__ void gemm_body(int id,
                                          const unsigned short* __restrict__ Ab,
                                          const unsigned short* __restrict__ WtL,
                                          unsigned short* __restrict__ Yb,
                                          unsigned short* As, unsigned short* Bs) {
    const int t = threadIdx.x;
    const int w = t >> 6, lane = t & 63;
    const int p = id & 3;
    const int m0 = (id >> 2) * 128;
    const unsigned short* WtP = WtL + p * 128 * 128;
    const int wr = w >> 1, wcol = w & 1;
    const int fr = lane & 15;
    const int fq = lane >> 4;
    const int gsw = (((lane & 3) ^ ((lane >> 2) & 3) ^ ((lane >> 4) & 3))) * 8;
    const int rsw = (fq ^ ((fr ^ (fr >> 2)) & 3)) * 8;
    f32x4 acc[4][4] = {};

    auto stage = [&](int s, int buf) {
        const int k0 = s * 32;
        #pragma unroll
        for (int i = 0; i < 2; ++i) {
            int row = i * 64 + w * 16 + (lane >> 2);
            int grow = m0 + row;
            if (grow > NN - 1) grow = NN - 1;
            const unsigned short* gA = Ab + (size_t)grow * DD + k0 + gsw;
            gload16(gA, (char*)As + buf * 8192 + i * 4096 + w * 1024);
            const unsigned short* gB = WtP + (size_t)row * 128 + k0 + gsw;
            gload16(gB, (char*)Bs + buf * 8192 + i * 4096 + w * 1024);
        }
    };

    stage(0, 0);
    #pragma unroll
    for (int s = 0; s < 4; ++s) {
        const int cur = s & 1;
        __syncthreads();
        if (s + 1 < 4) stage(s + 1, cur ^ 1);
        const unsigned short* As_c = As + cur * 4096;
        const unsigned short* Bs_c = Bs + cur * 4096;
        bf16x8 af[4], bfr[4];
        #pragma unroll
        for (int m = 0; m < 4; ++m)
            af[m] = *reinterpret_cast<const bf16x8*>(As_c + (wr * 64 + m * 16 + fr) * 32 + rsw);
        #pragma unroll
        for (int n = 0; n < 4; ++n)
            bfr[n] = *reinterpret_cast<const bf16x8*>(Bs_c + (wcol * 64 + n * 16 + fr) * 32 + rsw);
        #pragma unroll
        for (int m = 0; m < 4; ++m)
            #pragma unroll
            for (int n = 0; n < 4; ++n)
                acc[m][n] = __builtin_amdgcn_mfma_f32_16x16x32_bf16(af[m], bfr[n], acc[m][n], 0, 0, 0);
    }

    #pragma unroll
    for (int n = 0; n < 4; ++n) {
        int col = p * 128 + wcol * 64 + n * 16 + fr;
        #pragma unroll
        for (int m = 0; m < 4; ++m) {
            int rbase = m0 + wr * 64 + m * 16 + fq * 4;
            #pragma unroll
            for (int j = 0; j < 4; ++j) {
                int row = rbase + j;
                if (row < NN) Yb[(size_t)row * 512 + col] = f2bf(acc[m][n][j]);
            }
        }
    }
}

__global__ __launch_bounds__(256) void fill_gemm(
    const int* __restrict__ ei,
    const int* __restrict__ row_start,
    const int* __restrict__ bsum,
    const int* __restrict__ cnt,
    int* __restrict__ cursor,
    int2* __restrict__ bucket2,
    const unsigned short* __restrict__ Ab,
    const unsigned short* __restrict__ WtL,
    unsigned short* __restrict__ Yb)
{
    __shared__ __align__(16) unsigned short As[2 * 128 * 32];
    __shared__ __align__(16) unsigned short Bs[2 * 128 * 32];
    const int bid = blockIdx.x;
    int role, id;
    if (bid < 2 * NGEMM) { role = bid & 1; id = bid >> 1; }
    else { role = 1; id = NGEMM + (bid - 2 * NGEMM); }

    if (role == 0) {
        gemm_body(id, Ab, WtL, Yb, As, Bs);
    } else {
        int t = id * 256 + threadIdx.x;
        if (t < NEDGES) {
            int r = t / NE;
            int e = t - r * NE;
            int src = ei[(r * 2 + 0) * NE + e];
            int dst = ei[(r * 2 + 1) * NE + e];
            int i = dst * 3 + r;
            int pos = row_start[i] + bsum[i >> 10] + atomicAdd(&cursor[i], 1);
            float sc = 1.0f / (float)cnt[i];
            bucket2[pos] = make_int2((src << 10) | (r << 8), __float_as_int(sc));
        }
    }
}

// ================= standalone gemm (layer 1) =================
__global__ __launch_bounds__(256) void gemm_y(
    const unsigned short* __restrict__ Ab,
    const unsigned short* __restrict__ WtL,
    unsigned short* __restrict__ Yb)
{
    __shared__ __align__(16) unsigned short As[2 * 128 * 32];
    __shared__ __align__(16) unsigned short Bs[2 * 128 * 32];
    gemm_body(blockIdx.x, Ab, WtL, Yb, As, Bs);
}

// ================= fused gather: one wave per dst, 16 lanes/row x 4 rows =============
template <int FINAL>
__global__ __launch_bounds__(256) void gather_fused(
    const unsigned short* __restrict__ Yb,
    const int2* __restrict__ bucket2,
    const int* __restrict__ row_start,
    const int* __restrict__ bsum,
    const int* __restrict__ cnt,
    const float* __restrict__ biasL,
    const float* __restrict__ Wc,
    const float* __restrict__ bc,
    unsigned short* __restrict__ hout,
    float* __restrict__ out)
{
    int wid = (blockIdx.x * 256 + threadIdx.x) >> 6;
    int lane = threadIdx.x & 63;
    if (wid >= NN) return;
    const int g = lane >> 4;             // edge slot within 4-group
    const int q = lane & 15;             // 16B chunk within row
    const unsigned int qoff = q * 16u;
    const char* Yc = (const char*)Yb;
    const int r3 = wid * 3;
    const int base = row_start[r3] + bsum[r3 >> 10];
    const int degT = cnt[r3] + cnt[r3 + 1] + cnt[r3 + 2];

    float acc[8] = {};
    int e = 0;
    for (; e + 8 <= degT; e += 8) {
        int2 ma = bucket2[base + e + g];
        int2 mb = bucket2[base + e + 4 + g];
        uint4 va = *(const uint4*)(Yc + (unsigned)ma.x + qoff);
        uint4 vb = *(const uint4*)(Yc + (unsigned)mb.x + qoff);
        float sa = __int_as_float(ma.y);
        float sb = __int_as_float(mb.y);
        acc[0] = fmaf(bflo(va.x), sa, acc[0]); acc[1] = fmaf(bfhi(va.x), sa, acc[1]);
        acc[2] = fmaf(bflo(va.y), sa, acc[2]); acc[3] = fmaf(bfhi(va.y), sa, acc[3]);
        acc[4] = fmaf(bflo(va.z), sa, acc[4]); acc[5] = fmaf(bfhi(va.z), sa, acc[5]);
        acc[6] = fmaf(bflo(va.w), sa, acc[6]); acc[7] = fmaf(bfhi(va.w), sa, acc[7]);
        acc[0] = fmaf(bflo(vb.x), sb, acc[0]); acc[1] = fmaf(bfhi(vb.x), sb, acc[1]);
        acc[2] = fmaf(bflo(vb.y), sb, acc[2]); acc[3] = fmaf(bfhi(vb.y), sb, acc[3]);
        acc[4] = fmaf(bflo(vb.z), sb, acc[4]); acc[5] = fmaf(bfhi(vb.z), sb, acc[5]);
        acc[6] = fmaf(bflo(vb.w), sb, acc[6]); acc[7] = fmaf(bfhi(vb.w), sb, acc[7]);
    }
    for (; e < degT; e += 4) {
        if (e + g < degT) {
            int2 m = bucket2[base + e + g];
            uint4 v = *(const uint4*)(Yc + (unsigned)m.x + qoff);
            float s = __int_as_float(m.y);
            acc[0] = fmaf(bflo(v.x), s, acc[0]); acc[1] = fmaf(bfhi(v.x), s, acc[1]);
            acc[2] = fmaf(bflo(v.y), s, acc[2]); acc[3] = fmaf(bfhi(v.y), s, acc[3]);
            acc[4] = fmaf(bflo(v.z), s, acc[4]); acc[5] = fmaf(bfhi(v.z), s, acc[5]);
            acc[6] = fmaf(bflo(v.w), s, acc[6]); acc[7] = fmaf(bfhi(v.w), s, acc[7]);
        }
    }
    #pragma unroll
    for (int j = 0; j < 8; ++j) {
        acc[j] += __shfl_xor(acc[j], 16);
        acc[j] += __shfl_xor(acc[j], 32);
    }
    uint4 rv = *(const uint4*)(Yc + (size_t)wid * 1024u + 768u + qoff);
    acc[0] += bflo(rv.x); acc[1] += bfhi(rv.x);
    acc[2] += bflo(rv.y); acc[3] += bfhi(rv.y);
    acc[4] += bflo(rv.z); acc[5] += bfhi(rv.z);
    acc[6] += bflo(rv.w); acc[7] += bfhi(rv.w);
    float4 b0 = *(const float4*)(biasL + q * 8);
    float4 b1 = *(const float4*)(biasL + q * 8 + 4);
    acc[0] += b0.x; acc[1] += b0.y; acc[2] += b0.z; acc[3] += b0.w;
    acc[4] += b1.x; acc[5] += b1.y; acc[6] += b1.z; acc[7] += b1.w;

    if (!FINAL) {
        if (g == 0) {
            uint4 o;
            o.x = (unsigned)f2bf(fmaxf(acc[0], 0.f)) | ((unsigned)f2bf(fmaxf(acc[1], 0.f)) << 16);
            o.y = (unsigned)f2bf(fmaxf(acc[2], 0.f)) | ((unsigned)f2bf(fmaxf(acc[3], 0.f)) << 16);
            o.z = (unsigned)f2bf(fmaxf(acc[4], 0.f)) | ((unsigned)f2bf(fmaxf(acc[5], 0.f)) << 16);
            o.w = (unsigned)f2bf(fmaxf(acc[6], 0.f)) | ((unsigned)f2bf(fmaxf(acc[7], 0.f)) << 16);
            *reinterpret_cast<uint4*>(hout + (size_t)wid * DD + q * 8) = o;
        }
    } else {
        float4 w0 = *(const float4*)(Wc + q * 16);
        float4 w1 = *(const float4*)(Wc + q * 16 + 4);
        float4 w2 = *(const float4*)(Wc + q * 16 + 8);
        float4 w3 = *(const float4*)(Wc + q * 16 + 12);
        float p0 = acc[0] * w0.x + acc[1] * w0.z + acc[2] * w1.x + acc[3] * w1.z +
                   acc[4] * w2.x + acc[5] * w2.z + acc[6] * w3.x + acc[7] * w3.z;
        float p1 = acc[0] * w0.y + acc[1] * w0.w + acc[2] * w1.y + acc[3] * w1.w +
                   acc[4] * w2.y + acc[5] * w2.w + acc[6] * w3.y + acc[7] * w3.w;
        #pragma unroll
        for (int off = 1; off < 16; off <<= 1) {
            p0 += __shfl_xor(p0, off);
            p1 += __shfl_xor(p1, off);
        }
        if (lane == 0) {
            out[(size_t)wid * 2 + 0] = p0 + bc[0];
            out[(size_t)wid * 2 + 1] = p1 + bc[1];
        }
    }
}

extern "C" void kernel_launch(void* const* d_in, const int* in_sizes, int n_in,
                              void* d_out, int out_size, void* d_ws, size_t ws_size,
                              hipStream_t stream) {
    const float* x  = (const float*)d_in[0];
    const int*   ei = (const int*)d_in[1];
    const float* Wn = (const float*)d_in[2];
    const float* Wr = (const float*)d_in[3];
    const float* b  = (const float*)d_in[4];
    const float* Wc = (const float*)d_in[5];
    const float* bc = (const float*)d_in[6];
    float* out = (float*)d_out;

    char* p = (char*)d_ws;
    unsigned short* Yb  = (unsigned short*)p;  p += (size_t)NN * 512 * 2;        // 102.4 MB
    unsigned short* xb  = (unsigned short*)p;  p += (size_t)NN * DD * 2;         // 25.6 MB
    unsigned short* h1b = (unsigned short*)p;  p += (size_t)NN * DD * 2;         // 25.6 MB
    unsigned short* Wt2 = (unsigned short*)p;  p += (size_t)2 * 4 * 128 * 128 * 2;
    float* bias         = (float*)p;           p += 2 * 128 * 4;
    int2* bucket2       = (int2*)p;            p += (size_t)NEDGES * 8;          // 9.6 MB
    int* row_start      = (int*)p;             p += (size_t)NROWS * 4;
    int* bsum           = (int*)p;             p += 512 * 4;
    int* cnt            = (int*)p;             p += (size_t)NROWS * 4;
    int* cursor         = (int*)p;             p += (size_t)NROWS * 4;

    hipMemsetAsync(cnt, 0, NROWS * sizeof(int), stream);
    hipMemsetAsync(cursor, 0, NROWS * sizeof(int), stream);

    // 1. [cvt_x | weights | bias | csr_count]
    prep_count<<<NB_CVT + NB_WT + 1 + NB_CNT, 256, 0, stream>>>(
        x, Wn, Wr, b, ei, xb, Wt2, bias, cnt);

    // 2-3. scans
    scan1<<<SCAN_BLOCKS, 256, 0, stream>>>(cnt, row_start, bsum);
    scan2<<<1, 512, 0, stream>>>(bsum, SCAN_BLOCKS);

    // 4. [csr_fill | gemm_y layer 0] interleaved
    fill_gemm<<<2 * NGEMM + (NFILL - NGEMM), 256, 0, stream>>>(
        ei, row_start, bsum, cnt, cursor, bucket2, xb, Wt2, Yb);

    const int gatherBlocks = NN * 64 / 256;          // 25000 exact

    // 5. gather L0
    gather_fused<0><<<gatherBlocks, 256, 0, stream>>>(Yb, bucket2, row_start, bsum, cnt,
                                                      bias, nullptr, nullptr, h1b, nullptr);

    // 6. gemm L1
    gemm_y<<<NGEMM, 256, 0, stream>>>(h1b, Wt2 + (size_t)4 * 128 * 128, Yb);

    // 7. gather L1 + fused classifier
    gather_fused<1><<<gatherBlocks, 256, 0, stream>>>(Yb, bucket2, row_start, bsum, cnt,
                                                      bias + 128, Wc, bc, nullptr, out);
}